// Round 5
// baseline (257.636 us; speedup 1.0000x reference)
//
#include <hip/hip_runtime.h>
#include <cfloat>
#include <math.h>

// ---------------- problem constants ----------------
#define NBLOCKS 256
#define ESTR 516            // eT LDS row stride (dwords, 16B-aligned, staging-friendly)
#define XSTR 12             // per-wave x slice stride (dwords, 16B-aligned)

// output layout (flat concat, all float32)
#define O_LOSS 0
#define O_Q    1ull                         // 8388608 elements, NCHW
#define O_PERP 8388609ull
#define O_DIST 8388610ull                   // 131072 x 512
#define O_IDX  75497474ull                  // 131072
#define O_ENC  75628546ull                  // 131072 x 512

#define SMEM_BYTES ((64*ESTR + 8*64*XSTR) * 4)   // 156672 B

// ws layout: [0,2048) uint hist[512]; [2048,2056) double loss_sum; [2064,...) float sume2[512]

// ---------------- prep: zero accumulators, compute ||e_k||^2 (numpy pairwise order) ----
__global__ void vq_prep(const float* __restrict__ emb, unsigned int* __restrict__ hist,
                        double* __restrict__ lsum, float* __restrict__ sume2) {
    int k = threadIdx.x;   // 512 threads
    hist[k] = 0u;
    if (k == 0) *lsum = 0.0;
    float x[64];
    const float4* e4 = (const float4*)(emb + k * 64);
#pragma unroll
    for (int i = 0; i < 16; ++i) {
        float4 v = e4[i];
        x[4*i+0] = v.x; x[4*i+1] = v.y; x[4*i+2] = v.z; x[4*i+3] = v.w;
    }
    float r[8];
#pragma unroll
    for (int j = 0; j < 8; ++j) r[j] = x[j] * x[j];
#pragma unroll
    for (int i = 8; i < 64; i += 8)
#pragma unroll
        for (int j = 0; j < 8; ++j) r[j] += x[i+j] * x[i+j];
    sume2[k] = ((r[0]+r[1])+(r[2]+r[3])) + ((r[4]+r[5])+(r[6]+r[7]));
}

// ---------------- main kernel: fully wave-independent (no main-loop barriers) ----
__global__ __launch_bounds__(512, 2)
void vq_main(const float* __restrict__ in, const float* __restrict__ emb,
             float* __restrict__ out, unsigned int* __restrict__ hist,
             double* __restrict__ lsum, const float* __restrict__ sume2g) {
    extern __shared__ float smem[];
    float* eT = smem;                                  // [64][ESTR], shared read-only
    const int tid  = threadIdx.x;
    const int lane = tid & 63;
    const int w    = tid >> 6;                         // wave 0..7
    float* xw = smem + 64 * ESTR + w * (64 * XSTR);    // per-wave private [64][XSTR]

    const int n   = blockIdx.x >> 3;                   // image (512 rows/block, 4096/image)
    const int hwB = ((blockIdx.x & 7) << 9) + (w << 6);// this wave's 64-hw span start

    // lane mappings for the different phases
    const int cL = lane >> 1, hL = (lane & 1) << 2;    // x load/stage: c, hw-quad
    const int jS = lane & 7,  mS = lane >> 3;          // sumx2: acc-slot j, row m
    const int mQ = lane & 7,  cgQ = lane >> 3;         // quantize: hw-offset, c-group

    // ---- issue ALL global loads up front (none remain in the main loop) ----
    float4 ev16[16];
    {
        const float4* e4 = (const float4*)emb;
#pragma unroll
        for (int it = 0; it < 16; ++it) ev16[it] = e4[tid + 512 * it];
    }
    float4 pf[8][2];
#pragma unroll
    for (int t = 0; t < 8; ++t) {
        const float* p = in + (size_t)(n * 64 + cL) * 4096 + (hwB + 8 * t + hL);
        pf[t][0] = *(const float4*)p;
        pf[t][1] = *(const float4*)(p + 32 * 4096);
    }
    float4 se0 = *(const float4*)(sume2g + 4 * lane);
    float4 se1 = *(const float4*)(sume2g + 256 + 4 * lane);
    const float se[8] = {se0.x, se0.y, se0.z, se0.w, se1.x, se1.y, se1.z, se1.w};

    // ---- stage codebook transposed: eT[d][k] = emb[k*64+d]
#pragma unroll 4
    for (int it = 0; it < 16; ++it) {
        int idx4 = tid + 512 * it;
        int k  = idx4 >> 4;
        int dq = (idx4 & 15) << 2;
        float4 v = ev16[it];
        eT[(dq+0)*ESTR + k] = v.x;
        eT[(dq+1)*ESTR + k] = v.y;
        eT[(dq+2)*ESTR + k] = v.z;
        eT[(dq+3)*ESTR + k] = v.w;
    }
    __syncthreads();     // ONLY barrier: eT visible. Waves fully independent after this.

    double lacc = 0.0;

#pragma unroll
    for (int t = 0; t < 8; ++t) {
        const int hw0  = hwB + 8 * t;
        const int row0 = (n << 12) + hw0;              // flat NHWC row index

        // ---- stage this µtile's x into the wave-private LDS slice
        *(float4*)&xw[cL * XSTR + hL]        = pf[t][0];
        *(float4*)&xw[(cL + 32) * XSTR + hL] = pf[t][1];

        // ---- sumx2 per row: lane (mS,jS) builds np accumulator r[jS] for row mS,
        //      then 3-step butterfly reproduces ((r0+r1)+(r2+r3))+((r4+r5)+(r6+r7)) exactly
        float rj;
        { float v = xw[jS * XSTR + mS]; rj = v * v; }
#pragma unroll
        for (int i = 1; i < 8; ++i) { float v = xw[(8*i + jS) * XSTR + mS]; rj += v * v; }
        rj += __shfl_xor(rj, 1, 64);
        rj += __shfl_xor(rj, 2, 64);
        rj += __shfl_xor(rj, 4, 64);
        float sx[8];
#pragma unroll
        for (int m = 0; m < 8; ++m) sx[m] = __shfl(rj, 8 * m, 64);

        // ---- GEMM: thread tile 8 rows x 8 k (k = 256*(kk>>2) + 4*lane + (kk&3))
        float acc[8][8];
#pragma unroll
        for (int m = 0; m < 8; ++m)
#pragma unroll
            for (int kk = 0; kk < 8; ++kk) acc[m][kk] = 0.0f;

#pragma unroll 2
        for (int d = 0; d < 64; ++d) {
            float4 x0 = *(const float4*)&xw[d * XSTR];          // rows 0..3 (broadcast)
            float4 x1 = *(const float4*)&xw[d * XSTR + 4];      // rows 4..7
            float4 e0 = *(const float4*)&eT[d * ESTR + 4 * lane];        // k 4L..4L+3
            float4 e1 = *(const float4*)&eT[d * ESTR + 256 + 4 * lane];  // k 256+4L..
            float xv[8] = {x0.x, x0.y, x0.z, x0.w, x1.x, x1.y, x1.z, x1.w};
            float evv[8] = {e0.x, e0.y, e0.z, e0.w, e1.x, e1.y, e1.z, e1.w};
#pragma unroll
            for (int m = 0; m < 8; ++m)
#pragma unroll
                for (int kk = 0; kk < 8; ++kk)
                    acc[m][kk] = fmaf(xv[m], evv[kk], acc[m][kk]);
        }

        // ---- distances, 1KB-contiguous stores, in-wave lex argmin
        int bkk[8];                                    // wave-uniform after butterfly
#pragma unroll
        for (int m = 0; m < 8; ++m) {
            float dv[8];
            float bd = FLT_MAX; int bki = 0;
#pragma unroll
            for (int kk = 0; kk < 8; ++kk) {
                int k = ((kk & 4) << 6) + 4 * lane + (kk & 3);
                float ts = sx[m] + se[kk];             // fl(a+b) (np broadcast add)
                float dist = ts - 2.0f * acc[m][kk];   // fl(t - 2m)
                dv[kk] = dist;
                if (dist < bd) { bd = dist; bki = k; } // in-lane k ascending
            }
            float* dout = out + O_DIST + (size_t)(row0 + m) * 512;
            *(float4*)&dout[4 * lane]       = make_float4(dv[0], dv[1], dv[2], dv[3]);
            *(float4*)&dout[256 + 4 * lane] = make_float4(dv[4], dv[5], dv[6], dv[7]);
#pragma unroll
            for (int s = 1; s <= 32; s <<= 1) {        // lex (d, k) butterfly
                float od = __shfl_xor(bd, s, 64);
                int   ok = __shfl_xor(bki, s, 64);
                if (od < bd || (od == bd && ok < bki)) { bd = od; bki = ok; }
            }
            bkk[m] = bki;
        }

        // kbest for "my" row (lane&7) via static select tree (no runtime reg indexing)
        int s01 = (lane & 1) ? bkk[1] : bkk[0];
        int s23 = (lane & 1) ? bkk[3] : bkk[2];
        int s45 = (lane & 1) ? bkk[5] : bkk[4];
        int s67 = (lane & 1) ? bkk[7] : bkk[6];
        int s03 = (lane & 2) ? s23 : s01;
        int s47 = (lane & 2) ? s67 : s45;
        const int kbm = (lane & 4) ? s47 : s03;

        if (lane < 8) {
            out[O_IDX + row0 + lane] = (float)kbm;
            atomicAdd(&hist[kbm], 1u);
        }

        // ---- one-hot encodings (1KB-contiguous stores)
#pragma unroll
        for (int m = 0; m < 8; ++m) {
            const int kb = bkk[m];
            float* eout = out + O_ENC + (size_t)(row0 + m) * 512;
            float e0v[4], e1v[4];
#pragma unroll
            for (int q = 0; q < 4; ++q) {
                e0v[q] = (4 * lane + q == kb) ? 1.0f : 0.0f;
                e1v[q] = (256 + 4 * lane + q == kb) ? 1.0f : 0.0f;
            }
            *(float4*)&eout[4 * lane]       = make_float4(e0v[0], e0v[1], e0v[2], e0v[3]);
            *(float4*)&eout[256 + 4 * lane] = make_float4(e1v[0], e1v[1], e1v[2], e1v[3]);
        }

        // ---- quantized (straight-through, NCHW) + loss partial
#pragma unroll
        for (int i = 0; i < 8; ++i) {
            int c = 8 * i + cgQ;
            float x = xw[c * XSTR + mQ];
            float q = eT[c * ESTR + kbm];
            float dlt = q - x;                          // fl(q-x), as reference
            lacc += (double)(dlt * dlt);
            out[O_Q + (size_t)(n * 64 + c) * 4096 + hw0 + mQ] = x + dlt;  // x + (q-x)
        }
    }

    // ---- loss reduction: wave reduce then one atomic per wave
    double v = lacc;
    for (int s = 32; s >= 1; s >>= 1) v += __shfl_down(v, s, 64);
    if (lane == 0) atomicAdd(lsum, v);
}

// ---------------- final: perplexity + loss scalars ----------------
__global__ void vq_final(const unsigned int* __restrict__ hist,
                         const double* __restrict__ lsum, float* __restrict__ out) {
    __shared__ double part[8];
    int k = threadIdx.x;                    // 512 threads
    float p = (float)hist[k] / 131072.0f;   // exact (count * 2^-17)
    double v = (double)(p * logf(p + 1e-10f));
    for (int s = 32; s >= 1; s >>= 1) v += __shfl_down(v, s, 64);
    if ((k & 63) == 0) part[k >> 6] = v;
    __syncthreads();
    if (k == 0) {
        double S = 0.0;
#pragma unroll
        for (int i = 0; i < 8; ++i) S += part[i];
        out[O_PERP] = (float)exp(-S);
        float vl = (float)(*lsum / 8388608.0);
        out[O_LOSS] = vl + 0.25f * vl;      // q_latent + 0.25 * e_latent (equal values)
    }
}

// ---------------- launcher ----------------
extern "C" void kernel_launch(void* const* d_in, const int* in_sizes, int n_in,
                              void* d_out, int out_size, void* d_ws, size_t ws_size,
                              hipStream_t stream) {
    const float* in  = (const float*)d_in[0];   // (32,64,64,64) NCHW fp32
    const float* emb = (const float*)d_in[1];   // (512,64) fp32
    float* out = (float*)d_out;

    unsigned int* hist = (unsigned int*)d_ws;                    // 512 * 4 B
    double* lsum = (double*)((char*)d_ws + 2048);                // 8 B
    float* sume2 = (float*)((char*)d_ws + 2064);                 // 512 * 4 B

    hipFuncSetAttribute((const void*)vq_main,
                        hipFuncAttributeMaxDynamicSharedMemorySize, SMEM_BYTES);

    vq_prep<<<1, 512, 0, stream>>>(emb, hist, lsum, sume2);
    vq_main<<<NBLOCKS, 512, SMEM_BYTES, stream>>>(in, emb, out, hist, lsum, sume2);
    vq_final<<<1, 512, 0, stream>>>(hist, lsum, out);
}